// Round 1
// baseline (5154.367 us; speedup 1.0000x reference)
//
#include <hip/hip_runtime.h>
#include <hip/hip_bf16.h>

#define DEV __device__ __forceinline__

constexpr int B_ = 256;   // batch
constexpr int T_ = 512;   // time
constexpr int H_ = 128;   // GRU units
constexpr int K_ = 256;   // input dim per layer (D = 2H = 256 for all layers)
constexpr int G_ = 384;   // 3H
constexpr int M_ = B_ * T_;

using bf16 = __hip_bfloat16;

DEV float tof(float x) { return x; }
DEV float tof(bf16 x) { return __bfloat162float(x); }
DEV void stor(float* p, float v) { *p = v; }
DEV void stor(bf16* p, float v) { *p = __float2bfloat16(v); }

DEV float4 load4(const float* p) { return *(const float4*)p; }
DEV float4 load4(const bf16* p) {
  ushort4 u = *(const ushort4*)(const void*)p;
  union { unsigned int i; float f; } c;
  float4 f;
  c.i = ((unsigned)u.x) << 16; f.x = c.f;
  c.i = ((unsigned)u.y) << 16; f.y = c.f;
  c.i = ((unsigned)u.z) << 16; f.z = c.f;
  c.i = ((unsigned)u.w) << 16; f.w = c.f;
  return f;
}

DEV float fsigmoid(float x) { return 1.f / (1.f + __expf(-x)); }
DEV float ftanh(float x) {
  x = fminf(20.f, fmaxf(-20.f, x));
  float e = __expf(-2.f * x);
  return (1.f - e) / (1.f + e);
}

// ---------------------------------------------------------------------------
// Input projection GEMM: xp[dir][t][b][0:384] = A[b*T+t][:] @ W[dir] + b_i[dir]
// A: [M, 256] row-major (m = b*T + t). 128x128 tile, 8x8/thread, BK=16.
// ---------------------------------------------------------------------------
template <typename AT, typename XT>
__global__ __launch_bounds__(256, 2) void inproj_kernel(
    const AT* __restrict__ A, const float* __restrict__ Wbase,
    const float* __restrict__ bbase, XT* __restrict__ xp) {
  const int dir = blockIdx.z;
  const float* W = Wbase + dir * (K_ * G_);
  const float* bi = bbase + dir * (2 * G_);
  const int m0 = blockIdx.x * 128;
  const int n0 = blockIdx.y * 128;
  const int tid = threadIdx.x;
  const int tm = tid >> 4, tn = tid & 15;

  __shared__ __align__(16) float As[16][132];  // [k][m], padded
  __shared__ __align__(16) float Bs[16][132];  // [k][n], padded

  float acc[8][8] = {};

  const int arow = tid >> 1;        // 0..127
  const int ak = (tid & 1) * 8;     // 0 or 8
  const int bk = tid >> 4;          // 0..15
  const int bn = (tid & 15) * 4;    // 0..60

  for (int k0 = 0; k0 < K_; k0 += 16) {
    float4 a0 = load4(A + (m0 + arow) * K_ + k0 + ak);
    float4 a1 = load4(A + (m0 + arow) * K_ + k0 + ak + 4);
    float4 w0 = *(const float4*)(W + (k0 + bk) * G_ + n0 + bn);
    float4 w1 = *(const float4*)(W + (k0 + bk) * G_ + n0 + bn + 64);
    __syncthreads();
    As[ak + 0][arow] = a0.x; As[ak + 1][arow] = a0.y;
    As[ak + 2][arow] = a0.z; As[ak + 3][arow] = a0.w;
    As[ak + 4][arow] = a1.x; As[ak + 5][arow] = a1.y;
    As[ak + 6][arow] = a1.z; As[ak + 7][arow] = a1.w;
    *(float4*)&Bs[bk][bn] = w0;
    *(float4*)&Bs[bk][bn + 64] = w1;
    __syncthreads();
#pragma unroll
    for (int k = 0; k < 16; ++k) {
      float4 x0 = *(const float4*)&As[k][tm * 8];
      float4 x1 = *(const float4*)&As[k][tm * 8 + 4];
      float4 y0 = *(const float4*)&Bs[k][tn * 8];
      float4 y1 = *(const float4*)&Bs[k][tn * 8 + 4];
      float av[8] = {x0.x, x0.y, x0.z, x0.w, x1.x, x1.y, x1.z, x1.w};
      float bv[8] = {y0.x, y0.y, y0.z, y0.w, y1.x, y1.y, y1.z, y1.w};
#pragma unroll
      for (int i = 0; i < 8; ++i)
#pragma unroll
        for (int j = 0; j < 8; ++j) acc[i][j] = fmaf(av[i], bv[j], acc[i][j]);
    }
  }

  float bias[8];
#pragma unroll
  for (int j = 0; j < 8; ++j) bias[j] = bi[n0 + tn * 8 + j];
#pragma unroll
  for (int i = 0; i < 8; ++i) {
    const int m = m0 + tm * 8 + i;
    const int bb = m >> 9;          // T_ = 512
    const int t = m & (T_ - 1);
    XT* dst = xp + ((dir * T_ + t) * B_ + bb) * G_ + n0 + tn * 8;
#pragma unroll
    for (int j = 0; j < 8; ++j) stor(dst + j, acc[i][j] + bias[j]);
  }
}

// ---------------------------------------------------------------------------
// Recurrence. Grid (128, 2): blockIdx.y = dir, each block = 2 batch rows.
// 768 threads: column j = tid>>1 (0..383), half = tid&1 holds U[half*64.., j]
// in 64 VGPRs. h in LDS. shfl_xor(1) combines the two half-dot-products.
// ---------------------------------------------------------------------------
template <typename XT, typename ST, bool LAST>
__global__ __launch_bounds__(768) void rec_kernel(
    const XT* __restrict__ xp, const float* __restrict__ Ubase,
    const float* __restrict__ bbase, ST* __restrict__ outSeq,
    float* __restrict__ fin) {
  const int dir = blockIdx.y;
  const float* U = Ubase + dir * (H_ * G_);
  const float* bh = bbase + dir * (2 * G_) + G_;
  const int b0 = blockIdx.x * 2;
  const int tid = threadIdx.x;
  const int j = tid >> 1, half = tid & 1;

  __shared__ __align__(16) float hbuf[2][H_];
  __shared__ float rec_s[2][G_];

  float Ureg[64];
#pragma unroll
  for (int kk = 0; kk < 64; ++kk) Ureg[kk] = U[(half * 64 + kk) * G_ + j];
  const float bhj = bh[j];

  if (tid < 2 * H_) hbuf[tid >> 7][tid & (H_ - 1)] = 0.f;
  __syncthreads();

  const int grow = tid >> 7;        // gate-phase row (tid < 256)
  const int gu = tid & (H_ - 1);    // gate-phase unit

  for (int it = 0; it < T_; ++it) {
    const int t = dir ? (T_ - 1 - it) : it;

    // --- dot phase: rec[row][j] = sum_k h[row][k] * U[k][j] ---
    float s00 = 0.f, s01 = 0.f, s10 = 0.f, s11 = 0.f;
#pragma unroll
    for (int kk = 0; kk < 32; kk += 4) {
      float4 h0 = *(const float4*)&hbuf[0][half * 64 + kk];
      float4 h1 = *(const float4*)&hbuf[1][half * 64 + kk];
      s00 = fmaf(h0.x, Ureg[kk + 0], s00); s00 = fmaf(h0.y, Ureg[kk + 1], s00);
      s00 = fmaf(h0.z, Ureg[kk + 2], s00); s00 = fmaf(h0.w, Ureg[kk + 3], s00);
      s10 = fmaf(h1.x, Ureg[kk + 0], s10); s10 = fmaf(h1.y, Ureg[kk + 1], s10);
      s10 = fmaf(h1.z, Ureg[kk + 2], s10); s10 = fmaf(h1.w, Ureg[kk + 3], s10);
    }
#pragma unroll
    for (int kk = 32; kk < 64; kk += 4) {
      float4 h0 = *(const float4*)&hbuf[0][half * 64 + kk];
      float4 h1 = *(const float4*)&hbuf[1][half * 64 + kk];
      s01 = fmaf(h0.x, Ureg[kk + 0], s01); s01 = fmaf(h0.y, Ureg[kk + 1], s01);
      s01 = fmaf(h0.z, Ureg[kk + 2], s01); s01 = fmaf(h0.w, Ureg[kk + 3], s01);
      s11 = fmaf(h1.x, Ureg[kk + 0], s11); s11 = fmaf(h1.y, Ureg[kk + 1], s11);
      s11 = fmaf(h1.z, Ureg[kk + 2], s11); s11 = fmaf(h1.w, Ureg[kk + 3], s11);
    }
    float r0 = s00 + s01, r1 = s10 + s11;
    r0 += __shfl_xor(r0, 1);
    r1 += __shfl_xor(r1, 1);
    if (half == 0) {
      rec_s[0][j] = r0 + bhj;
      rec_s[1][j] = r1 + bhj;
    }
    __syncthreads();

    // --- gate phase (first 256 threads) ---
    if (tid < 2 * H_) {
      const int bb = b0 + grow;
      const XT* xrow = xp + ((dir * T_ + t) * B_ + bb) * G_;
      const float xz = tof(xrow[gu]);
      const float xr = tof(xrow[H_ + gu]);
      const float xh = tof(xrow[2 * H_ + gu]);
      const float rz = rec_s[grow][gu];
      const float rr = rec_s[grow][H_ + gu];
      const float rh = rec_s[grow][2 * H_ + gu];
      const float z = fsigmoid(xz + rz);
      const float r = fsigmoid(xr + rr);
      const float hh = ftanh(xh + r * rh);
      const float hold = hbuf[grow][gu];
      const float hn = z * hold + (1.f - z) * hh;
      hbuf[grow][gu] = hn;
      if constexpr (!LAST) {
        stor(outSeq + (bb * T_ + t) * (2 * H_) + dir * H_ + gu, hn);
      }
    }
    __syncthreads();
  }

  if constexpr (LAST) {
    if (tid < 2 * H_) fin[(b0 + grow) * (2 * H_) + dir * H_ + gu] = hbuf[grow][gu];
  }
}

// ---------------------------------------------------------------------------
// Dense head: out[b] = sigmoid(fin[b][:] . Wd + bd)
// ---------------------------------------------------------------------------
__global__ void dense_kernel(const float* __restrict__ fin,
                             const float* __restrict__ Wd,
                             const float* __restrict__ bd,
                             float* __restrict__ out) {
  __shared__ float w[2 * H_];
  const int tid = threadIdx.x;
  w[tid] = Wd[tid];
  __syncthreads();
  float s = bd[0];
  const float* row = fin + tid * (2 * H_);
#pragma unroll 8
  for (int jj = 0; jj < 2 * H_; ++jj) s = fmaf(row[jj], w[jj], s);
  out[tid] = 1.f / (1.f + __expf(-s));
}

// ---------------------------------------------------------------------------
template <typename XT, typename ST>
static void run_model(const float* x, const float* Ws, const float* Us,
                      const float* bs, const float* Wd, const float* bd,
                      float* out, char* ws, hipStream_t stream) {
  XT* xp = (XT*)ws;
  const size_t xpB = (size_t)2 * T_ * B_ * G_ * sizeof(XT);
  const size_t seqBy = (size_t)B_ * T_ * 2 * H_ * sizeof(ST);
  ST* sA = (ST*)(ws + xpB);
  ST* sB = (ST*)(ws + xpB + seqBy);
  float* fin = (float*)(ws + xpB + 2 * seqBy);

  const dim3 gG(M_ / 128, G_ / 128, 2);
  ST* sin = nullptr;
  ST* sout = sA;
  for (int l = 0; l < 3; ++l) {
    const float* Wl = Ws + (size_t)l * 2 * K_ * G_;
    const float* bl = bs + (size_t)l * 2 * 2 * G_;
    const float* Ul = Us + (size_t)l * 2 * H_ * G_;
    if (l == 0)
      inproj_kernel<float, XT><<<gG, 256, 0, stream>>>(x, Wl, bl, xp);
    else
      inproj_kernel<ST, XT><<<gG, 256, 0, stream>>>(sin, Wl, bl, xp);
    if (l < 2)
      rec_kernel<XT, ST, false>
          <<<dim3(B_ / 2, 2), 768, 0, stream>>>(xp, Ul, bl, sout, nullptr);
    else
      rec_kernel<XT, ST, true>
          <<<dim3(B_ / 2, 2), 768, 0, stream>>>(xp, Ul, bl, (ST*)nullptr, fin);
    sin = sout;
    sout = (sout == sA) ? sB : sA;
  }
  dense_kernel<<<1, B_, 0, stream>>>(fin, Wd, bd, out);
}

extern "C" void kernel_launch(void* const* d_in, const int* in_sizes, int n_in,
                              void* d_out, int out_size, void* d_ws,
                              size_t ws_size, hipStream_t stream) {
  const float* x = (const float*)d_in[0];
  const float* Ws = (const float*)d_in[1];
  const float* Us = (const float*)d_in[2];
  const float* bs = (const float*)d_in[3];
  const float* Wd = (const float*)d_in[4];
  const float* bd = (const float*)d_in[5];
  float* out = (float*)d_out;
  char* ws = (char*)d_ws;

  const size_t finB = (size_t)B_ * 2 * H_ * 4;
  const size_t seq32 = (size_t)B_ * T_ * 2 * H_ * 4;
  const size_t seq16 = seq32 / 2;
  const size_t xp32 = (size_t)2 * T_ * B_ * G_ * 4;
  const size_t xp16 = xp32 / 2;
  const size_t tier1 = xp32 + 2 * seq32 + finB;  // ~640 MiB, full fp32
  const size_t tier2 = xp16 + 2 * seq32 + finB;  // bf16 xp
  if (ws_size >= tier1)
    run_model<float, float>(x, Ws, Us, bs, Wd, bd, out, ws, stream);
  else if (ws_size >= tier2)
    run_model<bf16, float>(x, Ws, Us, bs, Wd, bd, out, ws, stream);
  else
    run_model<bf16, bf16>(x, Ws, Us, bs, Wd, bd, out, ws, stream);
}

// Round 2
// 3754.231 us; speedup vs baseline: 1.3729x; 1.3729x over previous
//
#include <hip/hip_runtime.h>
#include <hip/hip_bf16.h>

#define DEV __device__ __forceinline__

constexpr int B_ = 256;   // batch
constexpr int T_ = 512;   // time
constexpr int H_ = 128;   // GRU units
constexpr int K_ = 256;   // input dim per layer (D = 2H = 256 for all layers)
constexpr int G_ = 384;   // 3H
constexpr int M_ = B_ * T_;

using bf16 = __hip_bfloat16;

DEV float tof(float x) { return x; }
DEV float tof(bf16 x) { return __bfloat162float(x); }
DEV void stor(float* p, float v) { *p = v; }
DEV void stor(bf16* p, float v) { *p = __float2bfloat16(v); }

DEV float4 load4(const float* p) { return *(const float4*)p; }
DEV float4 load4(const bf16* p) {
  ushort4 u = *(const ushort4*)(const void*)p;
  union { unsigned int i; float f; } c;
  float4 f;
  c.i = ((unsigned)u.x) << 16; f.x = c.f;
  c.i = ((unsigned)u.y) << 16; f.y = c.f;
  c.i = ((unsigned)u.z) << 16; f.z = c.f;
  c.i = ((unsigned)u.w) << 16; f.w = c.f;
  return f;
}

DEV float fsigmoid(float x) { return 1.f / (1.f + __expf(-x)); }
DEV float ftanh(float x) {
  x = fminf(20.f, fmaxf(-20.f, x));
  float e = __expf(-2.f * x);
  return (1.f - e) / (1.f + e);
}

// Barrier that drains only LDS traffic (lgkmcnt), NOT global loads/stores.
// All inter-thread communication in rec_kernel is via LDS, so this is safe,
// and it keeps the xp prefetch loads + outSeq stores in flight across steps.
DEV void barrier_lds() {
  asm volatile("s_waitcnt lgkmcnt(0)\n\ts_barrier" ::: "memory");
}

// ---------------------------------------------------------------------------
// Input projection GEMM: xp[dir][t][b][0:384] = A[b*T+t][:] @ W[dir] + b_i[dir]
// A: [M, 256] row-major (m = b*T + t). 128x128 tile, 8x8/thread, BK=16.
// ---------------------------------------------------------------------------
template <typename AT, typename XT>
__global__ __launch_bounds__(256, 2) void inproj_kernel(
    const AT* __restrict__ A, const float* __restrict__ Wbase,
    const float* __restrict__ bbase, XT* __restrict__ xp) {
  const int dir = blockIdx.z;
  const float* W = Wbase + dir * (K_ * G_);
  const float* bi = bbase + dir * (2 * G_);
  const int m0 = blockIdx.x * 128;
  const int n0 = blockIdx.y * 128;
  const int tid = threadIdx.x;
  const int tm = tid >> 4, tn = tid & 15;

  __shared__ __align__(16) float As[16][132];  // [k][m], padded
  __shared__ __align__(16) float Bs[16][132];  // [k][n], padded

  float acc[8][8] = {};

  const int arow = tid >> 1;        // 0..127
  const int ak = (tid & 1) * 8;     // 0 or 8
  const int bk = tid >> 4;          // 0..15
  const int bn = (tid & 15) * 4;    // 0..60

  for (int k0 = 0; k0 < K_; k0 += 16) {
    float4 a0 = load4(A + (m0 + arow) * K_ + k0 + ak);
    float4 a1 = load4(A + (m0 + arow) * K_ + k0 + ak + 4);
    float4 w0 = *(const float4*)(W + (k0 + bk) * G_ + n0 + bn);
    float4 w1 = *(const float4*)(W + (k0 + bk) * G_ + n0 + bn + 64);
    __syncthreads();
    As[ak + 0][arow] = a0.x; As[ak + 1][arow] = a0.y;
    As[ak + 2][arow] = a0.z; As[ak + 3][arow] = a0.w;
    As[ak + 4][arow] = a1.x; As[ak + 5][arow] = a1.y;
    As[ak + 6][arow] = a1.z; As[ak + 7][arow] = a1.w;
    *(float4*)&Bs[bk][bn] = w0;
    *(float4*)&Bs[bk][bn + 64] = w1;
    __syncthreads();
#pragma unroll
    for (int k = 0; k < 16; ++k) {
      float4 x0 = *(const float4*)&As[k][tm * 8];
      float4 x1 = *(const float4*)&As[k][tm * 8 + 4];
      float4 y0 = *(const float4*)&Bs[k][tn * 8];
      float4 y1 = *(const float4*)&Bs[k][tn * 8 + 4];
      float av[8] = {x0.x, x0.y, x0.z, x0.w, x1.x, x1.y, x1.z, x1.w};
      float bv[8] = {y0.x, y0.y, y0.z, y0.w, y1.x, y1.y, y1.z, y1.w};
#pragma unroll
      for (int i = 0; i < 8; ++i)
#pragma unroll
        for (int j = 0; j < 8; ++j) acc[i][j] = fmaf(av[i], bv[j], acc[i][j]);
    }
  }

  float bias[8];
#pragma unroll
  for (int j = 0; j < 8; ++j) bias[j] = bi[n0 + tn * 8 + j];
#pragma unroll
  for (int i = 0; i < 8; ++i) {
    const int m = m0 + tm * 8 + i;
    const int bb = m >> 9;          // T_ = 512
    const int t = m & (T_ - 1);
    XT* dst = xp + ((dir * T_ + t) * B_ + bb) * G_ + n0 + tn * 8;
#pragma unroll
    for (int j = 0; j < 8; ++j) stor(dst + j, acc[i][j] + bias[j]);
  }
}

// ---------------------------------------------------------------------------
// Recurrence. Grid (128, 2): blockIdx.y = dir, each block = 2 batch rows.
// 768 threads. Column j = (tid&31)|((tid>>6)<<5)  (0..383); half = (tid>>5)&1
// holds U[half*64 + 0..63, j] in VGPRs. Lane mapping makes each 32-lane LDS
// phase read ONE broadcast address from hbuf (bank-conflict-free).
// xp for step t+1 is prefetched by gate threads during step t's dot phase.
// ---------------------------------------------------------------------------
template <typename XT, typename ST, bool LAST>
__global__ __launch_bounds__(768, 3) void rec_kernel(
    const XT* __restrict__ xp, const float* __restrict__ Ubase,
    const float* __restrict__ bbase, ST* __restrict__ outSeq,
    float* __restrict__ fin) {
  const int dir = blockIdx.y;
  const float* U = Ubase + dir * (H_ * G_);
  const float* bh = bbase + dir * (2 * G_) + G_;
  const int b0 = blockIdx.x * 2;
  const int tid = threadIdx.x;
  const int half = (tid >> 5) & 1;                 // wave lanes 0-31 vs 32-63
  const int j = (tid & 31) | ((tid >> 6) << 5);    // 0..383

  __shared__ __align__(16) float hbuf[2][H_];
  __shared__ float rec_s[2][G_];

  float Ureg[64];
#pragma unroll
  for (int kk = 0; kk < 64; ++kk) Ureg[kk] = U[(half * 64 + kk) * G_ + j];
  const float bhj = bh[j];

  const int grow = tid >> 7;        // gate-phase row (tid < 256)
  const int gu = tid & (H_ - 1);    // gate-phase unit
  const bool gateT = tid < 2 * H_;

  if (gateT) hbuf[grow][gu] = 0.f;

  const XT* xbase = xp + (size_t)(dir * T_) * B_ * G_;

  // prefetch step 0 (raw XT regs; conversion deferred to use site)
  XT xzc{}, xrc{}, xhc{};
  {
    const int t0 = dir ? (T_ - 1) : 0;
    if (gateT) {
      const XT* xr_ = xbase + ((size_t)t0 * B_ + b0 + grow) * G_ + gu;
      xzc = xr_[0];
      xrc = xr_[H_];
      xhc = xr_[2 * H_];
    }
  }
  barrier_lds();

  for (int it = 0; it < T_; ++it) {
    const int t = dir ? (T_ - 1 - it) : it;

    // --- prefetch xp for step it+1 (hidden under the dot phase) ---
    XT xzn = xzc, xrn = xrc, xhn = xhc;
    if (gateT && (it + 1 < T_)) {
      const int tn = dir ? (t - 1) : (t + 1);
      const XT* xr_ = xbase + ((size_t)tn * B_ + b0 + grow) * G_ + gu;
      xzn = xr_[0];
      xrn = xr_[H_];
      xhn = xr_[2 * H_];
    }

    // --- dot phase: rec[row][j] = sum_k h[row][k] * U[k][j] ---
    float a0[4] = {0.f, 0.f, 0.f, 0.f};
    float a1[4] = {0.f, 0.f, 0.f, 0.f};
#pragma unroll
    for (int q = 0; q < 16; ++q) {
      float4 h0 = *(const float4*)&hbuf[0][half * 64 + q * 4];
      float4 h1 = *(const float4*)&hbuf[1][half * 64 + q * 4];
      const int c = q & 3;
      a0[c] = fmaf(h0.x, Ureg[q * 4 + 0], a0[c]);
      a0[c] = fmaf(h0.y, Ureg[q * 4 + 1], a0[c]);
      a0[c] = fmaf(h0.z, Ureg[q * 4 + 2], a0[c]);
      a0[c] = fmaf(h0.w, Ureg[q * 4 + 3], a0[c]);
      a1[c] = fmaf(h1.x, Ureg[q * 4 + 0], a1[c]);
      a1[c] = fmaf(h1.y, Ureg[q * 4 + 1], a1[c]);
      a1[c] = fmaf(h1.z, Ureg[q * 4 + 2], a1[c]);
      a1[c] = fmaf(h1.w, Ureg[q * 4 + 3], a1[c]);
    }
    float r0 = (a0[0] + a0[1]) + (a0[2] + a0[3]);
    float r1 = (a1[0] + a1[1]) + (a1[2] + a1[3]);
    r0 += __shfl_xor(r0, 32);
    r1 += __shfl_xor(r1, 32);
    if (half == 0) {
      rec_s[0][j] = r0 + bhj;
      rec_s[1][j] = r1 + bhj;
    }
    barrier_lds();

    // --- gate phase (first 256 threads) ---
    if (gateT) {
      const float xz = tof(xzc);
      const float xr = tof(xrc);
      const float xh = tof(xhc);
      const float rz = rec_s[grow][gu];
      const float rr = rec_s[grow][H_ + gu];
      const float rh = rec_s[grow][2 * H_ + gu];
      const float z = fsigmoid(xz + rz);
      const float r = fsigmoid(xr + rr);
      const float hh = ftanh(xh + r * rh);
      const float hold = hbuf[grow][gu];
      const float hn = z * hold + (1.f - z) * hh;
      hbuf[grow][gu] = hn;
      if constexpr (!LAST) {
        stor(outSeq + ((b0 + grow) * T_ + t) * (2 * H_) + dir * H_ + gu, hn);
      }
      xzc = xzn;
      xrc = xrn;
      xhc = xhn;
    }
    barrier_lds();
  }

  if constexpr (LAST) {
    if (gateT) fin[(b0 + grow) * (2 * H_) + dir * H_ + gu] = hbuf[grow][gu];
  }
}

// ---------------------------------------------------------------------------
// Dense head: out[b] = sigmoid(fin[b][:] . Wd + bd)
// ---------------------------------------------------------------------------
__global__ void dense_kernel(const float* __restrict__ fin,
                             const float* __restrict__ Wd,
                             const float* __restrict__ bd,
                             float* __restrict__ out) {
  __shared__ float w[2 * H_];
  const int tid = threadIdx.x;
  w[tid] = Wd[tid];
  __syncthreads();
  float s = bd[0];
  const float* row = fin + tid * (2 * H_);
#pragma unroll 8
  for (int jj = 0; jj < 2 * H_; ++jj) s = fmaf(row[jj], w[jj], s);
  out[tid] = 1.f / (1.f + __expf(-s));
}

// ---------------------------------------------------------------------------
template <typename XT, typename ST>
static void run_model(const float* x, const float* Ws, const float* Us,
                      const float* bs, const float* Wd, const float* bd,
                      float* out, char* ws, hipStream_t stream) {
  XT* xp = (XT*)ws;
  const size_t xpB = (size_t)2 * T_ * B_ * G_ * sizeof(XT);
  const size_t seqBy = (size_t)B_ * T_ * 2 * H_ * sizeof(ST);
  ST* sA = (ST*)(ws + xpB);
  ST* sB = (ST*)(ws + xpB + seqBy);
  float* fin = (float*)(ws + xpB + 2 * seqBy);

  const dim3 gG(M_ / 128, G_ / 128, 2);
  ST* sin = nullptr;
  ST* sout = sA;
  for (int l = 0; l < 3; ++l) {
    const float* Wl = Ws + (size_t)l * 2 * K_ * G_;
    const float* bl = bs + (size_t)l * 2 * 2 * G_;
    const float* Ul = Us + (size_t)l * 2 * H_ * G_;
    if (l == 0)
      inproj_kernel<float, XT><<<gG, 256, 0, stream>>>(x, Wl, bl, xp);
    else
      inproj_kernel<ST, XT><<<gG, 256, 0, stream>>>(sin, Wl, bl, xp);
    if (l < 2)
      rec_kernel<XT, ST, false>
          <<<dim3(B_ / 2, 2), 768, 0, stream>>>(xp, Ul, bl, sout, nullptr);
    else
      rec_kernel<XT, ST, true>
          <<<dim3(B_ / 2, 2), 768, 0, stream>>>(xp, Ul, bl, (ST*)nullptr, fin);
    sin = sout;
    sout = (sout == sA) ? sB : sA;
  }
  dense_kernel<<<1, B_, 0, stream>>>(fin, Wd, bd, out);
}

extern "C" void kernel_launch(void* const* d_in, const int* in_sizes, int n_in,
                              void* d_out, int out_size, void* d_ws,
                              size_t ws_size, hipStream_t stream) {
  const float* x = (const float*)d_in[0];
  const float* Ws = (const float*)d_in[1];
  const float* Us = (const float*)d_in[2];
  const float* bs = (const float*)d_in[3];
  const float* Wd = (const float*)d_in[4];
  const float* bd = (const float*)d_in[5];
  float* out = (float*)d_out;
  char* ws = (char*)d_ws;

  const size_t finB = (size_t)B_ * 2 * H_ * 4;
  const size_t seq32 = (size_t)B_ * T_ * 2 * H_ * 4;
  const size_t xp32 = (size_t)2 * T_ * B_ * G_ * 4;
  const size_t xp16 = xp32 / 2;
  const size_t tier1 = xp32 + 2 * seq32 + finB;  // ~640 MiB, full fp32
  const size_t tier2 = xp16 + 2 * seq32 + finB;  // bf16 xp
  if (ws_size >= tier1)
    run_model<float, float>(x, Ws, Us, bs, Wd, bd, out, ws, stream);
  else if (ws_size >= tier2)
    run_model<bf16, float>(x, Ws, Us, bs, Wd, bd, out, ws, stream);
  else
    run_model<bf16, bf16>(x, Ws, Us, bs, Wd, bd, out, ws, stream);
}